// Round 10
// baseline (57.065 us; speedup 1.0000x reference)
//
#include <hip/hip_runtime.h>

#define TK 80    // TOKEN_DIM
#define TN 384   // EMB_DIM
#define BM 64    // rows per block

typedef __attribute__((ext_vector_type(8)))  __bf16 bf16x8;
typedef __attribute__((ext_vector_type(16))) float  f32x16;
typedef __attribute__((ext_vector_type(4)))  float  f32x4;

// f32 -> bf16 via compiler-native converts (v_cvt_pk_bf16_f32 pairs)
__device__ __forceinline__ bf16x8 pack8(float4 f0, float4 f1) {
    bf16x8 r;
    r[0] = (__bf16)f0.x; r[1] = (__bf16)f0.y;
    r[2] = (__bf16)f0.z; r[3] = (__bf16)f0.w;
    r[4] = (__bf16)f1.x; r[5] = (__bf16)f1.y;
    r[6] = (__bf16)f1.z; r[7] = (__bf16)f1.w;
    return r;
}

// ---------------------------------------------------------------------------
// Fused TokenEmbedder — direct-load MFMA, nt-outer, LDS-transpose epilogue.
// r10 vs r8 (best, 50.4 us):
//   * zero-init accs (bias does NOT gate MFMA — r9's regression cause)
//   * bias applied at readback as float4: (v4 + bias4) * m
//   * mask via sMask[64] LDS broadcast (no bpermute)
//   * cls override at readback (uniform branch)
//   * NON-TEMPORAL out stores: protect L2-resident W from the 201 MB
//     write-stream eviction (out is never re-read)
// NO min-waves bound (r5/r6: forcing 4 waves/EU => scratch spills, +270 MB).
// Block = 4 waves = 64 out rows; wave w owns out cols [96w, 96w+96).
// MFMA orientation (verified r2/r4/r8): D col = lane&31 = out col.
// ---------------------------------------------------------------------------
__global__ __launch_bounds__(256) void tok_fused(
    const float* __restrict__ feat,
    const unsigned char* __restrict__ amask,
    const int* __restrict__ gidx,
    const int* __restrict__ bidx,
    const float* __restrict__ W,
    const float* __restrict__ bias,
    const float* __restrict__ cls,
    float* __restrict__ out,
    float* __restrict__ out_amask,
    float* __restrict__ out_gidx,
    float* __restrict__ out_bidx,
    int B, int T)
{
    // wave-private transpose tiles [wave][mt][row][col] + block mask vector
    __shared__ __align__(16) float sT[4][2][32][32];   // 32 KB
    __shared__ float sMask[BM];

    const int tid   = threadIdx.x;
    const int lane  = tid & 63;
    const int wave  = tid >> 6;
    const int row0  = blockIdx.x * BM;
    const int colb  = wave * 96;
    const int lrow  = lane & 31;   // A-row (out row) / B-col (out col) in tile
    const int khalf = lane >> 5;   // 8-wide k-half selector

    // ---- amask storage detection (bool bytes vs int32): probe first 1 KB
    const unsigned int* w32 = (const unsigned int*)amask;
    unsigned int wprobe = w32[tid & 255];
    int bytemode = __syncthreads_or((int)((wprobe & 0xFFFFFF00u) != 0u));

    // ---- passthrough outputs + block mask vector in LDS
    if (tid < BM) {
        int r = row0 + tid;
        float m = bytemode ? (float)amask[r] : (float)(w32[r] & 1u);
        out_amask[r] = m;
        sMask[tid]   = m;
        out_bidx[r]  = (float)bidx[r];
    }
    if (blockIdx.x == 0 && tid < B) out_gidx[tid] = (float)gidx[tid];
    __syncthreads();   // sMask visible to all waves

    // ---- A fragments: direct global loads, hoisted once, reused across nt
    bf16x8 af[2][5];
    #pragma unroll
    for (int ks = 0; ks < 5; ++ks)
        #pragma unroll
        for (int mt = 0; mt < 2; ++mt) {
            const float* p = feat + (size_t)(row0 + mt * 32 + lrow) * TK
                           + ks * 16 + khalf * 8;
            af[mt][ks] = pack8(*(const float4*)p, *(const float4*)(p + 4));
        }

    const bool blkcls = (row0 % T) == 0;   // cls only at local row 0 (BM | T)
    const int  rr = lane >> 3;             // readback row within 8-row group
    const int  cc = (lane & 7) * 4;        // readback col group

    // ---- nt-outer: 2 accumulators live, W frags per nt
    #pragma unroll
    for (int nt = 0; nt < 3; ++nt) {
        const int c = colb + nt * 32 + lrow;

        bf16x8 wf[5];
        #pragma unroll
        for (int ks = 0; ks < 5; ++ks) {
            const float* p = W + (size_t)c * TK + ks * 16 + khalf * 8;
            wf[ks] = pack8(*(const float4*)p, *(const float4*)(p + 4));
        }

        f32x16 acc0 = (f32x16)0.0f, acc1 = (f32x16)0.0f;
        #pragma unroll
        for (int ks = 0; ks < 5; ++ks) {
            acc0 = __builtin_amdgcn_mfma_f32_32x32x16_bf16(af[0][ks], wf[ks], acc0, 0, 0, 0);
            acc1 = __builtin_amdgcn_mfma_f32_32x32x16_bf16(af[1][ks], wf[ks], acc1, 0, 0, 0);
        }

        // dump raw acc to wave-private LDS tile (no VALU between MFMA and write)
        // D layout: col = lane&31, row = 4*khalf + (reg&3) + 8*(reg>>2)
        #pragma unroll
        for (int mt = 0; mt < 2; ++mt) {
            const f32x16& a = mt ? acc1 : acc0;
            #pragma unroll
            for (int reg = 0; reg < 16; ++reg) {
                const int rl = 4 * khalf + (reg & 3) + 8 * (reg >> 2);  // 0..31
                sT[wave][mt][rl][lrow] = a[reg];
            }
        }

        // wide readback: (v + bias4) * mask, cls override, nt dwordx4 store
        const float4 bias4 = *(const float4*)(bias + colb + nt * 32 + cc);
        #pragma unroll
        for (int mt = 0; mt < 2; ++mt) {
            #pragma unroll
            for (int g = 0; g < 4; ++g) {
                const int rl = rr + 8 * g;
                float4 v4 = *(const float4*)&sT[wave][mt][rl][cc];
                const float m = sMask[mt * 32 + rl];
                v4.x = (v4.x + bias4.x) * m;
                v4.y = (v4.y + bias4.y) * m;
                v4.z = (v4.z + bias4.z) * m;
                v4.w = (v4.w + bias4.w) * m;
                if (blkcls) {
                    if ((mt == 0) & (rl == 0))
                        v4 = *(const float4*)(cls + colb + nt * 32 + cc);
                }
                float* p = out + (size_t)(row0 + mt * 32 + rl) * TN
                         + colb + nt * 32 + cc;
                f32x4 vv; vv[0] = v4.x; vv[1] = v4.y; vv[2] = v4.z; vv[3] = v4.w;
                __builtin_nontemporal_store(vv, (f32x4*)p);
            }
        }
    }
}

extern "C" void kernel_launch(void* const* d_in, const int* in_sizes, int n_in,
                              void* d_out, int out_size, void* d_ws, size_t ws_size,
                              hipStream_t stream) {
    const float*         feat  = (const float*)d_in[0];
    const unsigned char* amask = (const unsigned char*)d_in[1];
    const int*           gidx  = (const int*)d_in[2];
    const int*           bidx  = (const int*)d_in[3];
    const float*         W     = (const float*)d_in[4];
    const float*         bias  = (const float*)d_in[5];
    const float*         cls   = (const float*)d_in[6];

    const int BT = in_sizes[1];        // B*T rows (131072)
    const int B  = in_sizes[2];        // 16
    const int T  = BT / B;             // 8192

    float* out       = (float*)d_out;                  // [BT, 384]
    float* out_amask = out + (size_t)BT * TN;          // [BT]
    float* out_gidx  = out_amask + BT;                 // [B]
    float* out_bidx  = out_gidx + B;                   // [BT]

    tok_fused<<<BT / BM, 256, 0, stream>>>(
        feat, amask, gidx, bidx, W, bias, cls,
        out, out_amask, out_gidx, out_bidx, B, T);
}

// Round 11
// 53.715 us; speedup vs baseline: 1.0624x; 1.0624x over previous
//
#include <hip/hip_runtime.h>

#define TK 80    // TOKEN_DIM
#define TN 384   // EMB_DIM
#define BM 64    // rows per block

typedef __attribute__((ext_vector_type(8)))  __bf16 bf16x8;
typedef __attribute__((ext_vector_type(16))) float  f32x16;

// f32 -> bf16 via compiler-native converts (v_cvt_pk_bf16_f32 pairs)
__device__ __forceinline__ bf16x8 pack8(float4 f0, float4 f1) {
    bf16x8 r;
    r[0] = (__bf16)f0.x; r[1] = (__bf16)f0.y;
    r[2] = (__bf16)f0.z; r[3] = (__bf16)f0.w;
    r[4] = (__bf16)f1.x; r[5] = (__bf16)f1.y;
    r[6] = (__bf16)f1.z; r[7] = (__bf16)f1.w;
    return r;
}

// ---------------------------------------------------------------------------
// Fused TokenEmbedder — r8 structure (best, 50.4 us) with mask+bias folded
// into the GEMM via K-extension 80 -> 96 (6th ks step):
//   out = m*(feat.W + bias) = (m*feat).W + m*bias
//   A rows scaled by m (0/1 exact in bf16); virtual k=80 col: A=m, B=bias
//   (bias in bf16: |bias|~4e-3, err ~8e-6, negligible). k=81..95 zero.
// Epilogue is therefore VALU-FREE: raw acc -> ds_write -> ds_read_b128 ->
// global_store_dwordx4 (r8/r9/r10 showed VALU on the readback path is the
// regression mechanism; bpermute+VALU on dump path cost ~0 but are deleted).
// Regular stores (NT store regressed in r10). No min-waves bound (r5/r6:
// spill catastrophe). Block = 4 waves = 64 rows; wave w: cols [96w,96w+96).
// MFMA orientation (verified r2/r4/r8): D col = lane&31 = out col.
// ---------------------------------------------------------------------------
__global__ __launch_bounds__(256) void tok_fused(
    const float* __restrict__ feat,
    const unsigned char* __restrict__ amask,
    const int* __restrict__ gidx,
    const int* __restrict__ bidx,
    const float* __restrict__ W,
    const float* __restrict__ bias,
    const float* __restrict__ cls,
    float* __restrict__ out,
    float* __restrict__ out_amask,
    float* __restrict__ out_gidx,
    float* __restrict__ out_bidx,
    int B, int T)
{
    // wave-private transpose tiles [wave][mt][row][col]
    __shared__ __align__(16) float sT[4][2][32][32];   // 32 KB

    const int tid   = threadIdx.x;
    const int lane  = tid & 63;
    const int wave  = tid >> 6;
    const int row0  = blockIdx.x * BM;
    const int colb  = wave * 96;
    const int lrow  = lane & 31;   // A-row (out row) / B-col (out col) in tile
    const int khalf = lane >> 5;   // 8-wide k-half selector

    // ---- amask storage detection (bool bytes vs int32): probe first 1 KB
    const unsigned int* w32 = (const unsigned int*)amask;
    unsigned int wprobe = w32[tid & 255];
    int bytemode = __syncthreads_or((int)((wprobe & 0xFFFFFF00u) != 0u));

    // ---- passthrough outputs
    if (tid < BM) {
        int r = row0 + tid;
        out_amask[r] = bytemode ? (float)amask[r] : (float)(w32[r] & 1u);
        out_bidx[r]  = (float)bidx[r];
    }
    if (blockIdx.x == 0 && tid < B) out_gidx[tid] = (float)gidx[tid];

    // ---- per-lane mask of MY rows (recomputed from amask: no barrier needed)
    float mrow[2];
    #pragma unroll
    for (int mt = 0; mt < 2; ++mt) {
        int r = row0 + mt * 32 + lrow;
        mrow[mt] = bytemode ? (float)amask[r] : (float)(w32[r] & 1u);
    }

    // ---- A fragments (6 ks steps): ks 0..4 = m*feat slices; ks 5 = mask col
    bf16x8 af[2][6];
    #pragma unroll
    for (int ks = 0; ks < 5; ++ks)
        #pragma unroll
        for (int mt = 0; mt < 2; ++mt) {
            const float* p = feat + (size_t)(row0 + mt * 32 + lrow) * TK
                           + ks * 16 + khalf * 8;
            float4 f0 = *(const float4*)p, f1 = *(const float4*)(p + 4);
            const float m = mrow[mt];
            f0.x *= m; f0.y *= m; f0.z *= m; f0.w *= m;
            f1.x *= m; f1.y *= m; f1.z *= m; f1.w *= m;
            af[mt][ks] = pack8(f0, f1);
        }
    #pragma unroll
    for (int mt = 0; mt < 2; ++mt) {
        bf16x8 pad = (bf16x8)(__bf16)0.0f;
        if (khalf == 0) pad[0] = (__bf16)mrow[mt];   // virtual k=80 col = m
        af[mt][5] = pad;
    }

    const bool blkcls = (row0 % T) == 0;   // cls only at local row 0 (BM | T)
    const int  rr = lane >> 3;             // readback row within 8-row group
    const int  cc = (lane & 7) * 4;        // readback col group

    // ---- nt-outer: 2 accumulators live, W frags per nt
    #pragma unroll
    for (int nt = 0; nt < 3; ++nt) {
        const int c = colb + nt * 32 + lrow;

        bf16x8 wf[6];
        #pragma unroll
        for (int ks = 0; ks < 5; ++ks) {
            const float* p = W + (size_t)c * TK + ks * 16 + khalf * 8;
            wf[ks] = pack8(*(const float4*)p, *(const float4*)(p + 4));
        }
        {
            bf16x8 pad = (bf16x8)(__bf16)0.0f;
            if (khalf == 0) pad[0] = (__bf16)bias[c];  // virtual k=80 col = bias
            wf[5] = pad;
        }

        f32x16 acc0 = (f32x16)0.0f, acc1 = (f32x16)0.0f;
        #pragma unroll
        for (int ks = 0; ks < 6; ++ks) {
            acc0 = __builtin_amdgcn_mfma_f32_32x32x16_bf16(af[0][ks], wf[ks], acc0, 0, 0, 0);
            acc1 = __builtin_amdgcn_mfma_f32_32x32x16_bf16(af[1][ks], wf[ks], acc1, 0, 0, 0);
        }

        // dump raw acc to wave-private LDS tile (zero VALU)
        // D layout: col = lane&31, row = 4*khalf + (reg&3) + 8*(reg>>2)
        #pragma unroll
        for (int mt = 0; mt < 2; ++mt) {
            const f32x16& a = mt ? acc1 : acc0;
            #pragma unroll
            for (int reg = 0; reg < 16; ++reg) {
                const int rl = 4 * khalf + (reg & 3) + 8 * (reg >> 2);  // 0..31
                sT[wave][mt][rl][lrow] = a[reg];
            }
        }

        // pure readback: ds_read_b128 -> store_dwordx4 (no VALU on this path)
        #pragma unroll
        for (int mt = 0; mt < 2; ++mt) {
            #pragma unroll
            for (int g = 0; g < 4; ++g) {
                const int rl = rr + 8 * g;
                float4 v4 = *(const float4*)&sT[wave][mt][rl][cc];
                if (blkcls) {
                    if ((mt == 0) & (rl == 0))
                        v4 = *(const float4*)(cls + colb + nt * 32 + cc);
                }
                float* p = out + (size_t)(row0 + mt * 32 + rl) * TN
                         + colb + nt * 32 + cc;
                *(float4*)p = v4;
            }
        }
    }
}

extern "C" void kernel_launch(void* const* d_in, const int* in_sizes, int n_in,
                              void* d_out, int out_size, void* d_ws, size_t ws_size,
                              hipStream_t stream) {
    const float*         feat  = (const float*)d_in[0];
    const unsigned char* amask = (const unsigned char*)d_in[1];
    const int*           gidx  = (const int*)d_in[2];
    const int*           bidx  = (const int*)d_in[3];
    const float*         W     = (const float*)d_in[4];
    const float*         bias  = (const float*)d_in[5];
    const float*         cls   = (const float*)d_in[6];

    const int BT = in_sizes[1];        // B*T rows (131072)
    const int B  = in_sizes[2];        // 16
    const int T  = BT / B;             // 8192

    float* out       = (float*)d_out;                  // [BT, 384]
    float* out_amask = out + (size_t)BT * TN;          // [BT]
    float* out_gidx  = out_amask + BT;                 // [B]
    float* out_bidx  = out_gidx + B;                   // [BT]

    tok_fused<<<BT / BM, 256, 0, stream>>>(
        feat, amask, gidx, bidx, W, bias, cls,
        out, out_amask, out_gidx, out_bidx, B, T);
}

// Round 12
// 50.246 us; speedup vs baseline: 1.1357x; 1.0690x over previous
//
#include <hip/hip_runtime.h>

#define TK 80    // TOKEN_DIM
#define TN 384   // EMB_DIM
#define BM 64    // rows per block

typedef __attribute__((ext_vector_type(8)))  __bf16 bf16x8;
typedef __attribute__((ext_vector_type(16))) float  f32x16;

// f32 -> bf16 via compiler-native converts (v_cvt_pk_bf16_f32 pairs)
__device__ __forceinline__ bf16x8 pack8(float4 f0, float4 f1) {
    bf16x8 r;
    r[0] = (__bf16)f0.x; r[1] = (__bf16)f0.y;
    r[2] = (__bf16)f0.z; r[3] = (__bf16)f0.w;
    r[4] = (__bf16)f1.x; r[5] = (__bf16)f1.y;
    r[6] = (__bf16)f1.z; r[7] = (__bf16)f1.w;
    return r;
}

// ---------------------------------------------------------------------------
// Fused TokenEmbedder — REPRODUCTION RUN of round-8 best (50.4 us), verbatim.
// Structure: direct-load MFMA (no input LDS), nt-outer, per-wave LDS
// transpose epilogue with mask/bias applied on the DUMP path (shfl+VALU),
// readback kept pure ds_read_b128 -> store_dwordx4.
// Experiment record: mask/bias at readback (r9: 53.7), +NT stores (r10:
// 57.1), folded into GEMM via K-ext (r11: 53.7), direct scalar stores
// (r2/r4/r7: 58-61) ALL regress vs this. No min-waves bound (r5/r6: spills).
// Block = 4 waves = 64 out rows; wave w owns out cols [96w, 96w+96).
// MFMA orientation (verified r2/r4/r8): D col = lane&31 = out col.
// ---------------------------------------------------------------------------
__global__ __launch_bounds__(256) void tok_fused(
    const float* __restrict__ feat,
    const unsigned char* __restrict__ amask,
    const int* __restrict__ gidx,
    const int* __restrict__ bidx,
    const float* __restrict__ W,
    const float* __restrict__ bias,
    const float* __restrict__ cls,
    float* __restrict__ out,
    float* __restrict__ out_amask,
    float* __restrict__ out_gidx,
    float* __restrict__ out_bidx,
    int B, int T)
{
    // wave-private transpose tiles: [wave][mt][row][col], 32 KB total
    __shared__ __align__(16) float sT[4][2][32][32];

    const int tid   = threadIdx.x;
    const int lane  = tid & 63;
    const int wave  = tid >> 6;
    const int row0  = blockIdx.x * BM;
    const int colb  = wave * 96;
    const int lrow  = lane & 31;   // A-row (out row) / B-col (out col) in tile
    const int khalf = lane >> 5;   // 8-wide k-half selector

    // ---- amask storage detection (bool bytes vs int32): probe first 1 KB
    const unsigned int* w32 = (const unsigned int*)amask;
    unsigned int wprobe = w32[tid & 255];
    int bytemode = __syncthreads_or((int)((wprobe & 0xFFFFFF00u) != 0u));

    // ---- passthrough outputs
    if (tid < BM) {
        int r = row0 + tid;
        out_amask[r] = bytemode ? (float)amask[r] : (float)(w32[r] & 1u);
        out_bidx[r]  = (float)bidx[r];
    }
    if (blockIdx.x == 0 && tid < B) out_gidx[tid] = (float)gidx[tid];

    // ---- mask row vector: lane holds mask of row row0+lane (shfl in epilogue)
    float mv;
    {
        int r = row0 + lane;
        mv = bytemode ? (float)amask[r] : (float)(w32[r] & 1u);
    }

    // ---- A fragments: direct global loads, hoisted once, reused across nt.
    // Lanes l and l+32 cover one full 64-B line of a feat row per (mt,ks).
    bf16x8 af[2][5];
    #pragma unroll
    for (int ks = 0; ks < 5; ++ks)
        #pragma unroll
        for (int mt = 0; mt < 2; ++mt) {
            const float* p = feat + (size_t)(row0 + mt * 32 + lrow) * TK
                           + ks * 16 + khalf * 8;
            af[mt][ks] = pack8(*(const float4*)p, *(const float4*)(p + 4));
        }

    const bool blkcls = (row0 % T) == 0;   // cls only at row rlocal==0 (BM | T)

    // ---- nt-outer: 2 accumulators live, W frags per nt
    #pragma unroll
    for (int nt = 0; nt < 3; ++nt) {
        const int c = colb + nt * 32 + lrow;

        bf16x8 wf[5];
        #pragma unroll
        for (int ks = 0; ks < 5; ++ks) {
            const float* p = W + (size_t)c * TK + ks * 16 + khalf * 8;
            wf[ks] = pack8(*(const float4*)p, *(const float4*)(p + 4));
        }

        f32x16 acc0 = (f32x16)0.0f, acc1 = (f32x16)0.0f;
        #pragma unroll
        for (int ks = 0; ks < 5; ++ks) {
            acc0 = __builtin_amdgcn_mfma_f32_32x32x16_bf16(af[0][ks], wf[ks], acc0, 0, 0, 0);
            acc1 = __builtin_amdgcn_mfma_f32_32x32x16_bf16(af[1][ks], wf[ks], acc1, 0, 0, 0);
        }

        const float bvn = bias[c];
        const float cvn = cls[c];

        // reg-space epilogue -> wave-private LDS tiles
        // D layout: col = lane&31, row = 4*khalf + (reg&3) + 8*(reg>>2)
        #pragma unroll
        for (int mt = 0; mt < 2; ++mt) {
            const f32x16& a = mt ? acc1 : acc0;
            #pragma unroll
            for (int reg = 0; reg < 16; ++reg) {
                const int rl = 4 * khalf + (reg & 3) + 8 * (reg >> 2);  // 0..31
                const float m = __shfl(mv, mt * 32 + rl);
                float v = m * (a[reg] + bvn);
                if (blkcls & (mt == 0) & (rl == 0)) v = cvn;
                sT[wave][mt][rl][lrow] = v;
            }
        }

        // wide read-back + dwordx4 stores: lane l -> row (l>>3)+8g, cols (l&7)*4..+3
        const int rr = lane >> 3;          // 0..7
        const int cc = (lane & 7) * 4;     // 0,4,..,28
        #pragma unroll
        for (int mt = 0; mt < 2; ++mt) {
            #pragma unroll
            for (int g = 0; g < 4; ++g) {
                float4 v4 = *(const float4*)&sT[wave][mt][rr + 8 * g][cc];
                float* p = out + (size_t)(row0 + mt * 32 + rr + 8 * g) * TN
                         + colb + nt * 32 + cc;
                *(float4*)p = v4;
            }
        }
    }
}

extern "C" void kernel_launch(void* const* d_in, const int* in_sizes, int n_in,
                              void* d_out, int out_size, void* d_ws, size_t ws_size,
                              hipStream_t stream) {
    const float*         feat  = (const float*)d_in[0];
    const unsigned char* amask = (const unsigned char*)d_in[1];
    const int*           gidx  = (const int*)d_in[2];
    const int*           bidx  = (const int*)d_in[3];
    const float*         W     = (const float*)d_in[4];
    const float*         bias  = (const float*)d_in[5];
    const float*         cls   = (const float*)d_in[6];

    const int BT = in_sizes[1];        // B*T rows (131072)
    const int B  = in_sizes[2];        // 16
    const int T  = BT / B;             // 8192

    float* out       = (float*)d_out;                  // [BT, 384]
    float* out_amask = out + (size_t)BT * TN;          // [BT]
    float* out_gidx  = out_amask + BT;                 // [B]
    float* out_bidx  = out_gidx + B;                   // [BT]

    tok_fused<<<BT / BM, 256, 0, stream>>>(
        feat, amask, gidx, bidx, W, bias, cls,
        out, out_amask, out_gidx, out_bidx, B, T);
}